// Round 1
// baseline (5618.472 us; speedup 1.0000x reference)
//
#include <hip/hip_runtime.h>

#define N_USERS 60000
#define N_ITEMS 40000
#define N_TOTAL 100000
#define EMB 64
#define LN_EPS 1e-5f

// ego2[r,:] = c * filt[r] * (x[r,:] @ W) + x[r,:]
// One wave per row; lane j computes output dim j. W staged in LDS
// (lane-stride-1 -> 2 lanes/bank, conflict-free per m136).
__global__ void transform_kernel(const float* __restrict__ x,
                                 const float* __restrict__ W,
                                 const float* __restrict__ filt,
                                 const float* __restrict__ par,
                                 float* __restrict__ out, int nrows)
{
    __shared__ float Ws[EMB * EMB];
    const int tid = threadIdx.x;
    for (int i = tid; i < EMB * EMB; i += blockDim.x) Ws[i] = W[i];
    __syncthreads();
    const float c = par[0] * par[1];
    const int lane = tid & 63;
    const int wave = tid >> 6;            // 4 waves/block
    const int r0 = blockIdx.x * 32;       // 32 rows per block
    for (int rr = wave; rr < 32; rr += 4) {
        const int r = r0 + rr;
        if (r >= nrows) break;
        const float xv = x[(size_t)r * EMB + lane];
        float acc = 0.f;
#pragma unroll
        for (int k = 0; k < EMB; ++k) {
            const float xk = __shfl(xv, k, 64);
            acc += xk * Ws[k * EMB + lane];
        }
        out[(size_t)r * EMB + lane] = c * filt[r] * acc + xv;
    }
}

// dst[dst_idx[e], :] += vals[e] * src[src_idx[e], :]
// 16 lanes per edge, float4 gather (coalesced 256B/edge), 4 atomics/lane.
__global__ void spmm_scatter(const int* __restrict__ src_idx,
                             const int* __restrict__ dst_idx,
                             const float* __restrict__ vals,
                             const float* __restrict__ src,
                             float* __restrict__ dst, int nnz)
{
    const long long t = (long long)blockIdx.x * blockDim.x + threadIdx.x;
    const int e = (int)(t >> 4);
    const int l = (int)(t & 15);
    if (e >= nnz) return;
    const int s = src_idx[e];
    const int d = dst_idx[e];
    const float v = vals[e];
    const float4 xv = ((const float4*)(src + (size_t)s * EMB))[l];
    float* dp = dst + (size_t)d * EMB + l * 4;
    atomicAdd(dp + 0, v * xv.x);
    atomicAdd(dp + 1, v * xv.y);
    atomicAdd(dp + 2, v * xv.z);
    atomicAdd(dp + 3, v * xv.w);
}

// out[r,:] = (y[r,:]-mu)/sqrt(var+eps)*gamma + beta + ego[r,:]
// One wave per row; butterfly reduce over 64 lanes. Safe in-place (out==y):
// each lane reads its own element before writing it.
__global__ void ln_residual(const float* y,
                            const float* __restrict__ ego,
                            const float* __restrict__ gamma,
                            const float* __restrict__ beta,
                            float* out, int nrows)
{
    const int lane = threadIdx.x & 63;
    const int wave = threadIdx.x >> 6;
    const int r = blockIdx.x * 4 + wave;
    if (r >= nrows) return;
    const float v = y[(size_t)r * EMB + lane];
    float s = v, s2 = v * v;
#pragma unroll
    for (int off = 32; off > 0; off >>= 1) {
        s  += __shfl_down(s,  off, 64);
        s2 += __shfl_down(s2, off, 64);
    }
    s  = __shfl(s,  0, 64);
    s2 = __shfl(s2, 0, 64);
    const float mu  = s * (1.0f / EMB);
    const float var = s2 * (1.0f / EMB) - mu * mu;
    const float inv = rsqrtf(var + LN_EPS);
    out[(size_t)r * EMB + lane] =
        (v - mu) * inv * gamma[lane] + beta[lane] + ego[(size_t)r * EMB + lane];
}

extern "C" void kernel_launch(void* const* d_in, const int* in_sizes, int n_in,
                              void* d_out, int out_size, void* d_ws, size_t ws_size,
                              hipStream_t stream)
{
    const float* ego     = (const float*)d_in[0];
    const int*   rows    = (const int*)  d_in[1];
    const int*   cols    = (const int*)  d_in[2];
    const float* vals    = (const float*)d_in[3];
    const float* w_uu    = (const float*)d_in[4];
    const float* filt_uu = (const float*)d_in[5];
    const float* par_uu  = (const float*)d_in[6];
    const float* w_ii    = (const float*)d_in[7];
    const float* filt_ii = (const float*)d_in[8];
    const float* par_ii  = (const float*)d_in[9];
    const float* gamma   = (const float*)d_in[10];
    const float* beta    = (const float*)d_in[11];
    float* out = (float*)d_out;
    const int nnz = in_sizes[1];

    const size_t emb_bytes = (size_t)N_TOTAL * EMB * sizeof(float);
    float* ego2 = (float*)d_ws;                       // 25.6 MB
    float* h    = ego2 + (size_t)N_TOTAL * EMB;       // 25.6 MB

    // Zero accumulators (d_ws / d_out are poisoned 0xAA before every call).
    hipMemsetAsync(h,   0, emb_bytes, stream);
    hipMemsetAsync(out, 0, emb_bytes, stream);

    // Per-type dense transforms.
    transform_kernel<<<(N_USERS + 31) / 32, 256, 0, stream>>>(
        ego, w_uu, filt_uu, par_uu, ego2, N_USERS);
    transform_kernel<<<(N_ITEMS + 31) / 32, 256, 0, stream>>>(
        ego + (size_t)N_USERS * EMB, w_ii, filt_ii, par_ii,
        ego2 + (size_t)N_USERS * EMB, N_ITEMS);

    // h[col] += val * ego2[row]
    const long long thr = (long long)nnz * 16;
    const int blocks = (int)((thr + 255) / 256);
    spmm_scatter<<<blocks, 256, 0, stream>>>(rows, cols, vals, ego2, h, nnz);
    // y[row] += val * h[col]   (accumulate into d_out)
    spmm_scatter<<<blocks, 256, 0, stream>>>(cols, rows, vals, h, out, nnz);

    // LayerNorm + residual, in place on d_out.
    ln_residual<<<(N_TOTAL + 3) / 4, 256, 0, stream>>>(
        out, ego, gamma, beta, out, N_TOTAL);
}

// Round 2
// 1586.121 us; speedup vs baseline: 3.5423x; 3.5423x over previous
//
#include <hip/hip_runtime.h>

#define N_USERS 60000
#define N_ITEMS 40000
#define N_TOTAL 100000
#define EMB 64
#define LN_EPS 1e-5f

// ---------------------------------------------------------------------------
// ego2[r,:] = c * filt[r] * (x[r,:] @ W) + x[r,:]
__global__ void transform_kernel(const float* __restrict__ x,
                                 const float* __restrict__ W,
                                 const float* __restrict__ filt,
                                 const float* __restrict__ par,
                                 float* __restrict__ out, int nrows)
{
    __shared__ float Ws[EMB * EMB];
    const int tid = threadIdx.x;
    for (int i = tid; i < EMB * EMB; i += blockDim.x) Ws[i] = W[i];
    __syncthreads();
    const float c = par[0] * par[1];
    const int lane = tid & 63;
    const int wave = tid >> 6;            // 4 waves/block
    const int r0 = blockIdx.x * 32;       // 32 rows per block
    for (int rr = wave; rr < 32; rr += 4) {
        const int r = r0 + rr;
        if (r >= nrows) break;
        const float xv = x[(size_t)r * EMB + lane];
        float acc = 0.f;
#pragma unroll
        for (int k = 0; k < EMB; ++k) {
            const float xk = __shfl(xv, k, 64);
            acc += xk * Ws[k * EMB + lane];
        }
        out[(size_t)r * EMB + lane] = c * filt[r] * acc + xv;
    }
}

// ---------------------------------------------------------------------------
// Counting-sort machinery (fast path).
__global__ void hist_kernel(const int* __restrict__ rows,
                            const int* __restrict__ cols,
                            int* __restrict__ cnt_row,
                            int* __restrict__ cnt_col, int nnz)
{
    const int e = blockIdx.x * blockDim.x + threadIdx.x;
    if (e >= nnz) return;
    atomicAdd(&cnt_row[rows[e]], 1);
    atomicAdd(&cnt_col[cols[e]], 1);
}

// In-place exclusive scan of a0 (block 0) and a1 (block 1), n elements.
// shfl-based wave scan + LDS combine across the 4 waves.
__global__ void scan_kernel(int* __restrict__ a0, int* __restrict__ a1, int n)
{
    int* a = (blockIdx.x == 0) ? a0 : a1;
    __shared__ int wsum[4];
    __shared__ int carry_s;
    const int lane = threadIdx.x & 63;
    const int wv = threadIdx.x >> 6;
    if (threadIdx.x == 0) carry_s = 0;
    __syncthreads();
    for (int base = 0; base < n; base += 256) {
        const int i = base + threadIdx.x;
        const int v = (i < n) ? a[i] : 0;
        int incl = v;
#pragma unroll
        for (int off = 1; off < 64; off <<= 1) {
            const int t = __shfl_up(incl, off, 64);
            if (lane >= off) incl += t;
        }
        if (lane == 63) wsum[wv] = incl;
        __syncthreads();
        int woff = carry_s;
        for (int w = 0; w < wv; ++w) woff += wsum[w];
        if (i < n) a[i] = woff + incl - v;          // exclusive prefix
        const int total = wsum[0] + wsum[1] + wsum[2] + wsum[3];
        __syncthreads();
        if (threadIdx.x == 0) carry_s += total;
        __syncthreads();
    }
}

// Scatter edges into sorted-by-key order. cursor holds exclusive starts on
// entry and END offsets on exit (start of bin k+1 == end of bin k), which is
// exactly what spmm_pull consumes.
__global__ void build_pairs(const int* __restrict__ key,
                            const int* __restrict__ other,
                            const float* __restrict__ vals,
                            int* __restrict__ cursor,
                            int2* __restrict__ pairs, int nnz)
{
    const int e = blockIdx.x * blockDim.x + threadIdx.x;
    if (e >= nnz) return;
    const int p = atomicAdd(&cursor[key[e]], 1);
    pairs[p] = make_int2(other[e], __float_as_int(vals[e]));
}

// dst[r,:] = sum over edges of bin r: val * src[other,:]
// One wave per row, lane = dim. Register accumulation, single write.
__global__ void spmm_pull(const int* __restrict__ ends,
                          const int2* __restrict__ pairs,
                          const float* __restrict__ src,
                          float* __restrict__ dst, int nrows)
{
    const int lane = threadIdx.x & 63;
    const int wv = threadIdx.x >> 6;
    const int r = blockIdx.x * 4 + wv;
    if (r >= nrows) return;
    const int beg = (r == 0) ? 0 : ends[r - 1];
    const int end = ends[r];
    float acc = 0.f;
    int j = beg;
    for (; j + 2 <= end; j += 2) {       // unroll-2: two gathers in flight
        const int2 p0 = pairs[j];
        const int2 p1 = pairs[j + 1];
        const float s0 = src[(size_t)p0.x * EMB + lane];
        const float s1 = src[(size_t)p1.x * EMB + lane];
        acc += __int_as_float(p0.y) * s0;
        acc += __int_as_float(p1.y) * s1;
    }
    if (j < end) {
        const int2 p = pairs[j];
        acc += __int_as_float(p.y) * src[(size_t)p.x * EMB + lane];
    }
    dst[(size_t)r * EMB + lane] = acc;
}

// ---------------------------------------------------------------------------
// Fallback (round-1) atomic scatter, used only if ws_size is too small.
__global__ void spmm_scatter(const int* __restrict__ src_idx,
                             const int* __restrict__ dst_idx,
                             const float* __restrict__ vals,
                             const float* __restrict__ src,
                             float* __restrict__ dst, int nnz)
{
    const long long t = (long long)blockIdx.x * blockDim.x + threadIdx.x;
    const int e = (int)(t >> 4);
    const int l = (int)(t & 15);
    if (e >= nnz) return;
    const int s = src_idx[e];
    const int d = dst_idx[e];
    const float v = vals[e];
    const float4 xv = ((const float4*)(src + (size_t)s * EMB))[l];
    float* dp = dst + (size_t)d * EMB + l * 4;
    atomicAdd(dp + 0, v * xv.x);
    atomicAdd(dp + 1, v * xv.y);
    atomicAdd(dp + 2, v * xv.z);
    atomicAdd(dp + 3, v * xv.w);
}

// ---------------------------------------------------------------------------
// out[r,:] = LN(y[r,:]) * gamma + beta + ego[r,:]   (in-place safe: out==y)
__global__ void ln_residual(const float* y,
                            const float* __restrict__ ego,
                            const float* __restrict__ gamma,
                            const float* __restrict__ beta,
                            float* out, int nrows)
{
    const int lane = threadIdx.x & 63;
    const int wave = threadIdx.x >> 6;
    const int r = blockIdx.x * 4 + wave;
    if (r >= nrows) return;
    const float v = y[(size_t)r * EMB + lane];
    float s = v, s2 = v * v;
#pragma unroll
    for (int off = 32; off > 0; off >>= 1) {
        s  += __shfl_down(s,  off, 64);
        s2 += __shfl_down(s2, off, 64);
    }
    s  = __shfl(s,  0, 64);
    s2 = __shfl(s2, 0, 64);
    const float mu  = s * (1.0f / EMB);
    const float var = s2 * (1.0f / EMB) - mu * mu;
    const float inv = rsqrtf(var + LN_EPS);
    out[(size_t)r * EMB + lane] =
        (v - mu) * inv * gamma[lane] + beta[lane] + ego[(size_t)r * EMB + lane];
}

extern "C" void kernel_launch(void* const* d_in, const int* in_sizes, int n_in,
                              void* d_out, int out_size, void* d_ws, size_t ws_size,
                              hipStream_t stream)
{
    const float* ego     = (const float*)d_in[0];
    const int*   rows    = (const int*)  d_in[1];
    const int*   cols    = (const int*)  d_in[2];
    const float* vals    = (const float*)d_in[3];
    const float* w_uu    = (const float*)d_in[4];
    const float* filt_uu = (const float*)d_in[5];
    const float* par_uu  = (const float*)d_in[6];
    const float* w_ii    = (const float*)d_in[7];
    const float* filt_ii = (const float*)d_in[8];
    const float* par_ii  = (const float*)d_in[9];
    const float* gamma   = (const float*)d_in[10];
    const float* beta    = (const float*)d_in[11];
    float* out = (float*)d_out;
    const int nnz = in_sizes[1];

    const size_t emb_elems = (size_t)N_TOTAL * EMB;
    const size_t emb_bytes = emb_elems * sizeof(float);
    float* ego2 = (float*)d_ws;                 // [0, 25.6 MB)
    float* h    = ego2 + emb_elems;             // [25.6, 51.2 MB)

    // Fast-path workspace: ego2 + h + pairs(nnz*8B) + 2 offset arrays.
    const size_t need = 2 * emb_bytes + (size_t)nnz * sizeof(int2)
                        + 2 * (size_t)N_TOTAL * sizeof(int);

    const int eb = (nnz + 255) / 256;           // edge-parallel blocks
    const int rb = (N_TOTAL + 3) / 4;           // row-parallel blocks (wave/row)

    if (ws_size >= need) {
        // ---------------- fast path: counting sort + pull ----------------
        int2* pairs    = (int2*)(h + emb_elems);          // [51.2, 76.8 MB)
        int*  offs_col = (int*)(pairs + nnz);             // 400 KB
        int*  offs_row = offs_col + N_TOTAL;              // 400 KB

        hipMemsetAsync(offs_col, 0, 2 * (size_t)N_TOTAL * sizeof(int), stream);

        hist_kernel<<<eb, 256, 0, stream>>>(rows, cols, offs_row, offs_col, nnz);
        scan_kernel<<<2, 256, 0, stream>>>(offs_col, offs_row, N_TOTAL);

        // Dense transforms (independent of sort).
        transform_kernel<<<(N_USERS + 31) / 32, 256, 0, stream>>>(
            ego, w_uu, filt_uu, par_uu, ego2, N_USERS);
        transform_kernel<<<(N_ITEMS + 31) / 32, 256, 0, stream>>>(
            ego + (size_t)N_USERS * EMB, w_ii, filt_ii, par_ii,
            ego2 + (size_t)N_USERS * EMB, N_ITEMS);

        // Pass 1: h[c] = sum val * ego2[r]  — group by col, payload = row.
        build_pairs<<<eb, 256, 0, stream>>>(cols, rows, vals, offs_col, pairs, nnz);
        spmm_pull<<<rb, 256, 0, stream>>>(offs_col, pairs, ego2, h, N_TOTAL);

        // Pass 2: y[r] = sum val * h[c]  — group by row, payload = col.
        // Reuses the pairs buffer (pass-1 pull has completed in-stream).
        build_pairs<<<eb, 256, 0, stream>>>(rows, cols, vals, offs_row, pairs, nnz);
        spmm_pull<<<rb, 256, 0, stream>>>(offs_row, pairs, h, out, N_TOTAL);
    } else {
        // ---------------- fallback: atomic scatter (round-1) -------------
        hipMemsetAsync(h,   0, emb_bytes, stream);
        hipMemsetAsync(out, 0, emb_bytes, stream);

        transform_kernel<<<(N_USERS + 31) / 32, 256, 0, stream>>>(
            ego, w_uu, filt_uu, par_uu, ego2, N_USERS);
        transform_kernel<<<(N_ITEMS + 31) / 32, 256, 0, stream>>>(
            ego + (size_t)N_USERS * EMB, w_ii, filt_ii, par_ii,
            ego2 + (size_t)N_USERS * EMB, N_ITEMS);

        const long long thr = (long long)nnz * 16;
        const int sblocks = (int)((thr + 255) / 256);
        spmm_scatter<<<sblocks, 256, 0, stream>>>(rows, cols, vals, ego2, h, nnz);
        spmm_scatter<<<sblocks, 256, 0, stream>>>(cols, rows, vals, h, out, nnz);
    }

    // LayerNorm + residual, in place on d_out.
    ln_residual<<<rb, 256, 0, stream>>>(out, ego, gamma, beta, out, N_TOTAL);
}

// Round 3
// 1183.778 us; speedup vs baseline: 4.7462x; 1.3399x over previous
//
#include <hip/hip_runtime.h>

#define N_USERS 60000
#define N_ITEMS 40000
#define N_TOTAL 100000
#define EMB 64
#define LN_EPS 1e-5f
#define NCHUNKS ((N_TOTAL + 255) / 256)   // 391

// ---------------------------------------------------------------------------
// ego2[r,:] = c * filt[r] * (x[r,:] @ W) + x[r,:]
__global__ void transform_kernel(const float* __restrict__ x,
                                 const float* __restrict__ W,
                                 const float* __restrict__ filt,
                                 const float* __restrict__ par,
                                 float* __restrict__ out, int nrows)
{
    __shared__ float Ws[EMB * EMB];
    const int tid = threadIdx.x;
    for (int i = tid; i < EMB * EMB; i += blockDim.x) Ws[i] = W[i];
    __syncthreads();
    const float c = par[0] * par[1];
    const int lane = tid & 63;
    const int wave = tid >> 6;            // 4 waves/block
    const int r0 = blockIdx.x * 32;       // 32 rows per block
    for (int rr = wave; rr < 32; rr += 4) {
        const int r = r0 + rr;
        if (r >= nrows) break;
        const float xv = x[(size_t)r * EMB + lane];
        float acc = 0.f;
#pragma unroll
        for (int k = 0; k < EMB; ++k) {
            const float xk = __shfl(xv, k, 64);
            acc += xk * Ws[k * EMB + lane];
        }
        out[(size_t)r * EMB + lane] = c * filt[r] * acc + xv;
    }
}

// ---------------------------------------------------------------------------
// Counting-sort machinery.
__global__ void hist_kernel(const int* __restrict__ rows,
                            const int* __restrict__ cols,
                            int* __restrict__ cnt_row,
                            int* __restrict__ cnt_col, int nnz)
{
    const int e = blockIdx.x * blockDim.x + threadIdx.x;
    if (e >= nnz) return;
    atomicAdd(&cnt_row[rows[e]], 1);
    atomicAdd(&cnt_col[cols[e]], 1);
}

// Phase A: per-256-chunk sums. grid = (NCHUNKS, 2).
__global__ void chunk_sums(const int* __restrict__ a0,
                           const int* __restrict__ a1,
                           int* __restrict__ bsum, int n)
{
    const int* a = blockIdx.y ? a1 : a0;
    const int i = blockIdx.x * 256 + threadIdx.x;
    int v = (i < n) ? a[i] : 0;
    __shared__ int ws[4];
    const int lane = threadIdx.x & 63;
    const int wv = threadIdx.x >> 6;
#pragma unroll
    for (int off = 32; off > 0; off >>= 1) v += __shfl_down(v, off, 64);
    if (lane == 0) ws[wv] = v;
    __syncthreads();
    if (threadIdx.x == 0)
        bsum[blockIdx.y * NCHUNKS + blockIdx.x] = ws[0] + ws[1] + ws[2] + ws[3];
}

// Phase B: exclusive scan of each array's chunk sums (391 elems, 2 iters).
// grid = 2 blocks.
__global__ void scan_sums(int* __restrict__ bsum)
{
    int* a = bsum + blockIdx.x * NCHUNKS;
    __shared__ int wsum[4];
    __shared__ int carry_s;
    const int lane = threadIdx.x & 63;
    const int wv = threadIdx.x >> 6;
    if (threadIdx.x == 0) carry_s = 0;
    __syncthreads();
    for (int base = 0; base < NCHUNKS; base += 256) {
        const int i = base + threadIdx.x;
        const int v = (i < NCHUNKS) ? a[i] : 0;
        int incl = v;
#pragma unroll
        for (int off = 1; off < 64; off <<= 1) {
            const int t = __shfl_up(incl, off, 64);
            if (lane >= off) incl += t;
        }
        if (lane == 63) wsum[wv] = incl;
        __syncthreads();
        int woff = carry_s;
        for (int w = 0; w < wv; ++w) woff += wsum[w];
        if (i < NCHUNKS) a[i] = woff + incl - v;    // exclusive prefix
        const int total = wsum[0] + wsum[1] + wsum[2] + wsum[3];
        __syncthreads();
        if (threadIdx.x == 0) carry_s += total;
        __syncthreads();
    }
}

// Phase C: block-local exclusive scan + chunk offset. grid = (NCHUNKS, 2).
__global__ void scan_apply(int* __restrict__ a0, int* __restrict__ a1,
                           const int* __restrict__ bsum, int n)
{
    int* a = blockIdx.y ? a1 : a0;
    const int chunk_off = bsum[blockIdx.y * NCHUNKS + blockIdx.x];
    const int i = blockIdx.x * 256 + threadIdx.x;
    const int v = (i < n) ? a[i] : 0;
    const int lane = threadIdx.x & 63;
    const int wv = threadIdx.x >> 6;
    int incl = v;
#pragma unroll
    for (int off = 1; off < 64; off <<= 1) {
        const int t = __shfl_up(incl, off, 64);
        if (lane >= off) incl += t;
    }
    __shared__ int wsum[4];
    if (lane == 63) wsum[wv] = incl;
    __syncthreads();
    int woff = chunk_off;
    for (int w = 0; w < wv; ++w) woff += wsum[w];
    if (i < n) a[i] = woff + incl - v;              // exclusive prefix
}

// Scatter edges into sorted-by-key order. cursor: exclusive starts on entry,
// bin END offsets on exit (consumed by spmm_pull).
__global__ void build_pairs(const int* __restrict__ key,
                            const int* __restrict__ other,
                            const float* __restrict__ vals,
                            int* __restrict__ cursor,
                            int2* __restrict__ pairs, int nnz)
{
    const int e = blockIdx.x * blockDim.x + threadIdx.x;
    if (e >= nnz) return;
    const int p = atomicAdd(&cursor[key[e]], 1);
    pairs[p] = make_int2(other[e], __float_as_int(vals[e]));
}

// dst[r,:] = sum over edges of bin r: val * src[other,:]
// One wave per row. 4 edge-groups x 16 lanes x float4: 4 independent 256B
// gathers in flight per wave (8 with unroll-2). Cross-group combine: shfl_xor.
__global__ void spmm_pull(const int* __restrict__ ends,
                          const int2* __restrict__ pairs,
                          const float* __restrict__ src,
                          float* __restrict__ dst, int nrows)
{
    const int lane = threadIdx.x & 63;
    const int wv = threadIdx.x >> 6;
    const int r = blockIdx.x * 4 + wv;
    if (r >= nrows) return;
    const int beg = (r == 0) ? 0 : ends[r - 1];
    const int end = ends[r];
    const int g = lane >> 4;                 // edge group 0..3
    const int l = lane & 15;                 // float4 column 0..15
    float4 acc = make_float4(0.f, 0.f, 0.f, 0.f);
    int j = beg + g;
    for (; j + 4 < end; j += 8) {            // 2 edges per group per iter
        const int2 p0 = pairs[j];
        const int2 p1 = pairs[j + 4];
        const float4 s0 = ((const float4*)(src + (size_t)p0.x * EMB))[l];
        const float4 s1 = ((const float4*)(src + (size_t)p1.x * EMB))[l];
        const float v0 = __int_as_float(p0.y);
        const float v1 = __int_as_float(p1.y);
        acc.x += v0 * s0.x; acc.y += v0 * s0.y;
        acc.z += v0 * s0.z; acc.w += v0 * s0.w;
        acc.x += v1 * s1.x; acc.y += v1 * s1.y;
        acc.z += v1 * s1.z; acc.w += v1 * s1.w;
    }
    if (j < end) {
        const int2 p = pairs[j];
        const float4 s = ((const float4*)(src + (size_t)p.x * EMB))[l];
        const float v = __int_as_float(p.y);
        acc.x += v * s.x; acc.y += v * s.y;
        acc.z += v * s.z; acc.w += v * s.w;
    }
    // combine the 4 edge-groups (lanes differing in bits 4,5)
#pragma unroll
    for (int m = 16; m <= 32; m <<= 1) {
        acc.x += __shfl_xor(acc.x, m, 64);
        acc.y += __shfl_xor(acc.y, m, 64);
        acc.z += __shfl_xor(acc.z, m, 64);
        acc.w += __shfl_xor(acc.w, m, 64);
    }
    if (g == 0) ((float4*)(dst + (size_t)r * EMB))[l] = acc;
}

// ---------------------------------------------------------------------------
// Fallback (round-1) atomic scatter, used only if ws_size is too small.
__global__ void spmm_scatter(const int* __restrict__ src_idx,
                             const int* __restrict__ dst_idx,
                             const float* __restrict__ vals,
                             const float* __restrict__ src,
                             float* __restrict__ dst, int nnz)
{
    const long long t = (long long)blockIdx.x * blockDim.x + threadIdx.x;
    const int e = (int)(t >> 4);
    const int l = (int)(t & 15);
    if (e >= nnz) return;
    const int s = src_idx[e];
    const int d = dst_idx[e];
    const float v = vals[e];
    const float4 xv = ((const float4*)(src + (size_t)s * EMB))[l];
    float* dp = dst + (size_t)d * EMB + l * 4;
    atomicAdd(dp + 0, v * xv.x);
    atomicAdd(dp + 1, v * xv.y);
    atomicAdd(dp + 2, v * xv.z);
    atomicAdd(dp + 3, v * xv.w);
}

// ---------------------------------------------------------------------------
// out[r,:] = LN(y[r,:]) * gamma + beta + ego[r,:]   (in-place safe: out==y)
__global__ void ln_residual(const float* y,
                            const float* __restrict__ ego,
                            const float* __restrict__ gamma,
                            const float* __restrict__ beta,
                            float* out, int nrows)
{
    const int lane = threadIdx.x & 63;
    const int wave = threadIdx.x >> 6;
    const int r = blockIdx.x * 4 + wave;
    if (r >= nrows) return;
    const float v = y[(size_t)r * EMB + lane];
    float s = v, s2 = v * v;
#pragma unroll
    for (int off = 32; off > 0; off >>= 1) {
        s  += __shfl_down(s,  off, 64);
        s2 += __shfl_down(s2, off, 64);
    }
    s  = __shfl(s,  0, 64);
    s2 = __shfl(s2, 0, 64);
    const float mu  = s * (1.0f / EMB);
    const float var = s2 * (1.0f / EMB) - mu * mu;
    const float inv = rsqrtf(var + LN_EPS);
    out[(size_t)r * EMB + lane] =
        (v - mu) * inv * gamma[lane] + beta[lane] + ego[(size_t)r * EMB + lane];
}

extern "C" void kernel_launch(void* const* d_in, const int* in_sizes, int n_in,
                              void* d_out, int out_size, void* d_ws, size_t ws_size,
                              hipStream_t stream)
{
    const float* ego     = (const float*)d_in[0];
    const int*   rows    = (const int*)  d_in[1];
    const int*   cols    = (const int*)  d_in[2];
    const float* vals    = (const float*)d_in[3];
    const float* w_uu    = (const float*)d_in[4];
    const float* filt_uu = (const float*)d_in[5];
    const float* par_uu  = (const float*)d_in[6];
    const float* w_ii    = (const float*)d_in[7];
    const float* filt_ii = (const float*)d_in[8];
    const float* par_ii  = (const float*)d_in[9];
    const float* gamma   = (const float*)d_in[10];
    const float* beta    = (const float*)d_in[11];
    float* out = (float*)d_out;
    const int nnz = in_sizes[1];

    const size_t emb_elems = (size_t)N_TOTAL * EMB;
    const size_t emb_bytes = emb_elems * sizeof(float);
    float* ego2 = (float*)d_ws;                 // [0, 25.6 MB)
    float* h    = ego2 + emb_elems;             // [25.6, 51.2 MB)

    // Fast-path workspace (identical to round 2 — keeps the branch stable).
    const size_t need = 2 * emb_bytes + (size_t)nnz * sizeof(int2)
                        + 2 * (size_t)N_TOTAL * sizeof(int);

    const int eb = (nnz + 255) / 256;           // edge-parallel blocks
    const int rb = (N_TOTAL + 3) / 4;           // row-parallel blocks (wave/row)

    if (ws_size >= need) {
        // ---------------- fast path: counting sort + pull ----------------
        int2* pairs    = (int2*)(h + emb_elems);          // [51.2, 76.8 MB)
        int*  offs_col = (int*)(pairs + nnz);             // 400 KB
        int*  offs_row = offs_col + N_TOTAL;              // 400 KB
        // bsum aliases the head of the (not-yet-written) pairs region; it is
        // dead before build_pairs runs (same-stream ordering).
        int*  bsum     = (int*)pairs;                     // 2*NCHUNKS ints

        hipMemsetAsync(offs_col, 0, 2 * (size_t)N_TOTAL * sizeof(int), stream);

        hist_kernel<<<eb, 256, 0, stream>>>(rows, cols, offs_row, offs_col, nnz);

        // Parallel exclusive scan of offs_col & offs_row.
        chunk_sums<<<dim3(NCHUNKS, 2), 256, 0, stream>>>(offs_col, offs_row,
                                                         bsum, N_TOTAL);
        scan_sums<<<2, 256, 0, stream>>>(bsum);
        scan_apply<<<dim3(NCHUNKS, 2), 256, 0, stream>>>(offs_col, offs_row,
                                                         bsum, N_TOTAL);

        // Dense transforms.
        transform_kernel<<<(N_USERS + 31) / 32, 256, 0, stream>>>(
            ego, w_uu, filt_uu, par_uu, ego2, N_USERS);
        transform_kernel<<<(N_ITEMS + 31) / 32, 256, 0, stream>>>(
            ego + (size_t)N_USERS * EMB, w_ii, filt_ii, par_ii,
            ego2 + (size_t)N_USERS * EMB, N_ITEMS);

        // Pass 1: h[c] = sum val * ego2[r]  — group by col, payload = row.
        build_pairs<<<eb, 256, 0, stream>>>(cols, rows, vals, offs_col, pairs, nnz);
        spmm_pull<<<rb, 256, 0, stream>>>(offs_col, pairs, ego2, h, N_TOTAL);

        // Pass 2: y[r] = sum val * h[c]  — group by row, payload = col.
        build_pairs<<<eb, 256, 0, stream>>>(rows, cols, vals, offs_row, pairs, nnz);
        spmm_pull<<<rb, 256, 0, stream>>>(offs_row, pairs, h, out, N_TOTAL);
    } else {
        // ---------------- fallback: atomic scatter (round-1) -------------
        hipMemsetAsync(h,   0, emb_bytes, stream);
        hipMemsetAsync(out, 0, emb_bytes, stream);

        transform_kernel<<<(N_USERS + 31) / 32, 256, 0, stream>>>(
            ego, w_uu, filt_uu, par_uu, ego2, N_USERS);
        transform_kernel<<<(N_ITEMS + 31) / 32, 256, 0, stream>>>(
            ego + (size_t)N_USERS * EMB, w_ii, filt_ii, par_ii,
            ego2 + (size_t)N_USERS * EMB, N_ITEMS);

        const long long thr = (long long)nnz * 16;
        const int sblocks = (int)((thr + 255) / 256);
        spmm_scatter<<<sblocks, 256, 0, stream>>>(rows, cols, vals, ego2, h, nnz);
        spmm_scatter<<<sblocks, 256, 0, stream>>>(cols, rows, vals, h, out, nnz);
    }

    // LayerNorm + residual, in place on d_out.
    ln_residual<<<rb, 256, 0, stream>>>(out, ego, gamma, beta, out, N_TOTAL);
}